// Round 3
// baseline (343.217 us; speedup 1.0000x reference)
//
#include <hip/hip_runtime.h>

// out[b,c,h,w] = x[b,c,h,w] * (1 - mask[b,0,h,w])   (MASK_VALUE == 0)
// B=64, C=3, H=W=512, fp32. Pure memory-bound elementwise blend.
//
// R7 = R4 data path (per-thread mask skip, NT loads+stores) with a
// persistent grid-stride structure (Guideline 11):
//   - 2048 blocks x 256 threads = 8 blocks/CU resident, one generation,
//     no block-turnover latency re-exposure.
//   - 8 chunks per thread; chunk c handles plane b = c*8 + (g>>16),
//     v = g & 65535  (consecutive threads -> consecutive v: coalesced).
//   - 1-deep mask pipeline: chunk c+1's mask load issues BEFORE chunk
//     c's x loads/stores -> mask latency hides under x/store work and
//     every wave keeps mask-reads + x-reads + writes mixed in flight
//     (steady stream mix instead of lockstep phase convoys).
// Register cost of the pipeline: +4 VGPRs (one fvec4), unlike R5's +48.
//
// Traffic unchanged: 67 MB mask + ~0.65*201 MB x + 201 MB out ~ 400 MB.

#define HW   (512 * 512)
#define C_   3
#define B_   64
#define VPP  (HW / 4)           // 65536 vec4s per plane
#define NTHR (2048 * 256)       // 524288 threads
#define CH   ((B_ * VPP) / NTHR)  // 8 chunks per thread

typedef float fvec4 __attribute__((ext_vector_type(4)));

__global__ __launch_bounds__(256) void random_mask_blend(
    const fvec4* __restrict__ x,     // B*C*VPP vec4s
    const fvec4* __restrict__ mask,  // B*1*VPP vec4s
    fvec4* __restrict__ out)
{
    const int g  = blockIdx.x * 256 + threadIdx.x;  // [0, 524288)
    const int v  = g & (VPP - 1);                   // pixel-vec4 within plane
    const int b0 = g >> 16;                         // [0, 8)

    // prime the pipeline: mask for chunk 0
    fvec4 m_next = __builtin_nontemporal_load(
        &mask[(long long)b0 * VPP + v]);

#pragma unroll
    for (int c = 0; c < CH; ++c) {
        const fvec4 m = m_next;
        if (c + 1 < CH) {
            // prefetch next chunk's mask before this chunk's x/store work
            m_next = __builtin_nontemporal_load(
                &mask[(long long)((c + 1) * 8 + b0) * VPP + v]);
        }

        const int b = c * 8 + b0;
        const long long base = ((long long)b * C_) * VPP + v;

        if (m.x + m.y + m.z + m.w == 4.0f) {
            const fvec4 z = {0.0f, 0.0f, 0.0f, 0.0f};
#pragma unroll
            for (int ch = 0; ch < C_; ++ch)
                __builtin_nontemporal_store(z, &out[base + (long long)ch * VPP]);
        } else {
            const fvec4 w = 1.0f - m;
#pragma unroll
            for (int ch = 0; ch < C_; ++ch) {
                const long long idx = base + (long long)ch * VPP;
                const fvec4 xv = __builtin_nontemporal_load(&x[idx]);
                __builtin_nontemporal_store(xv * w, &out[idx]);
            }
        }
    }
}

extern "C" void kernel_launch(void* const* d_in, const int* in_sizes, int n_in,
                              void* d_out, int out_size, void* d_ws, size_t ws_size,
                              hipStream_t stream) {
    const fvec4* x    = (const fvec4*)d_in[0];
    const fvec4* mask = (const fvec4*)d_in[1];
    fvec4* out        = (fvec4*)d_out;

    dim3 grid(2048);
    dim3 block(256);
    random_mask_blend<<<grid, block, 0, stream>>>(x, mask, out);
}

// Round 4
// 336.564 us; speedup vs baseline: 1.0198x; 1.0198x over previous
//
#include <hip/hip_runtime.h>

// out[b,c,h,w] = x[b,c,h,w] * (1 - mask[b,0,h,w])   (MASK_VALUE == 0)
// B=64, C=3, H=W=512. Pure memory-bound elementwise blend.
//
// R8 = exact revert to R4, the best-measured variant (337.6 us).
// Session A/B ledger (all vs R4):
//   R5 4-chunk MLP restructure:      +9.4 us  (VGPR bloat)
//   R6 cacheable stores:             +1.9 us  (null -> MALL zero-sum)
//   R7 persistent grid-stride:       +5.6 us  (null -> no convoy effect)
// Conclusion: kernel portion is HBM-traffic-bound at its mandatory
// ~400 MB (64 MiB mask + ~125 MiB unmasked x + 192 MiB out); the
// remaining timed-region cost is harness poison fills (2 x 805 MB at
// ~120 us, 83-84% HBM peak per rocprof) + dispatch overhead.
//
// Data-dependent x-load skip: mask is exactly {0,1} in huge contiguous
// regions; where all 4 mask vals of a thread are 1, out = 0 and x is
// never fetched (exec-masked lanes don't fetch cachelines) -> ~35% of
// x reads (~70 MB) skipped. All data single-touch -> nontemporal.

#define HW   (512 * 512)        // 262144 elements per plane
#define C_   3
#define B_   64
#define VPP  (HW / 4)           // 65536 vec4s per plane

typedef float fvec4 __attribute__((ext_vector_type(4)));

__global__ __launch_bounds__(256) void random_mask_blend(
    const fvec4* __restrict__ x,     // B*C*VPP vec4s
    const fvec4* __restrict__ mask,  // B*1*VPP vec4s
    fvec4* __restrict__ out)
{
    const int v = blockIdx.x * blockDim.x + threadIdx.x;  // [0, VPP)
    const int b = blockIdx.y;

    const fvec4 mv = __builtin_nontemporal_load(&mask[(long long)b * VPP + v]);
    const long long base = ((long long)b * C_) * VPP + v;

    // Fully-masked thread: out = 0 for all 3 channels, skip the x loads.
    if (mv.x + mv.y + mv.z + mv.w == 4.0f) {
        const fvec4 z = {0.0f, 0.0f, 0.0f, 0.0f};
#pragma unroll
        for (int c = 0; c < C_; ++c)
            __builtin_nontemporal_store(z, &out[base + (long long)c * VPP]);
    } else {
        const fvec4 w = 1.0f - mv;
#pragma unroll
        for (int c = 0; c < C_; ++c) {
            const long long idx = base + (long long)c * VPP;
            const fvec4 xv = __builtin_nontemporal_load(&x[idx]);
            __builtin_nontemporal_store(xv * w, &out[idx]);
        }
    }
}

extern "C" void kernel_launch(void* const* d_in, const int* in_sizes, int n_in,
                              void* d_out, int out_size, void* d_ws, size_t ws_size,
                              hipStream_t stream) {
    const fvec4* x    = (const fvec4*)d_in[0];
    const fvec4* mask = (const fvec4*)d_in[1];
    fvec4* out        = (fvec4*)d_out;

    dim3 grid(VPP / 256, B_);   // (256, 64)
    dim3 block(256);
    random_mask_blend<<<grid, block, 0, stream>>>(x, mask, out);
}